// Round 3
// baseline (688.906 us; speedup 1.0000x reference)
//
#include <hip/hip_runtime.h>
#include <stdint.h>

// Problem dims
#define Bg 256
#define Tg 64
#define Pg 10
#define NG 8   // graphs per sgcn block
#define GL 4   // lstm games per block

typedef _Float16 half2v __attribute__((ext_vector_type(2)));

// fp16 packed dot product with fp32 accumulate: c + a.x*b.x + a.y*b.y
__device__ __forceinline__ float dot2(uint32_t a, uint32_t b, float c) {
#if __has_builtin(__builtin_amdgcn_fdot2)
    return __builtin_amdgcn_fdot2(__builtin_bit_cast(half2v, a),
                                  __builtin_bit_cast(half2v, b), c, false);
#else
    float d;
    asm("v_dot2_f32_f16 %0, %1, %2, %3"
        : "=v"(d) : "v"(a), "v"(b), "v"(c));
    return d;
#endif
}

__device__ __forceinline__ uint32_t pkh2(float lo, float hi) {
    half2v h; h.x = (_Float16)lo; h.y = (_Float16)hi;
    return __builtin_bit_cast(uint32_t, h);
}
__device__ __forceinline__ uint16_t f2h(float f) {
    _Float16 h = (_Float16)f;
    return __builtin_bit_cast(uint16_t, h);
}
__device__ __forceinline__ float h2f(uint16_t u) {
    _Float16 h = __builtin_bit_cast(_Float16, u);
    return (float)h;
}
__device__ __forceinline__ float2 up2(uint32_t u) {
    half2v h = __builtin_bit_cast(half2v, u);
    return make_float2((float)h.x, (float)h.y);
}
__device__ __forceinline__ float sigmoidf_(float x) {
    return 1.0f / (1.0f + __expf(-x));
}
__device__ __forceinline__ float fast_tanh(float x) {
    float e = __expf(2.0f * x);
    return (e - 1.0f) / (e + 1.0f);
}

// ---------------------------------------------------------------------------
// SGCN v6: 1024 threads, rows 0-4 / 5-9 split across the two 8-wave halves
// (5 rows/thread). Cross-row exchange via LDS reuse: Ys lives in H16b, Us in
// Xsu, so LDS stays 80,896 B -> 2 blocks/CU = 32 waves = 100% occupancy
// (was 44%). __launch_bounds__(1024,8) caps VGPR at 64; deep accumulation is
// 2-pass (U12, then U34+Dd) to keep peak liveness ~35 regs.
// ---------------------------------------------------------------------------
__global__ __launch_bounds__(1024, 8) void sgcn_kernel(
    const float* __restrict__ x,
    const float* __restrict__ A_pos,
    const float* __restrict__ A_neg,
    const float* __restrict__ Wpb,
    const float* __restrict__ bpb,
    const float* __restrict__ Wnb,
    const float* __restrict__ bnb,
    const float* __restrict__ Wpd,
    const float* __restrict__ bpd,
    const float* __restrict__ Wnd,
    const float* __restrict__ bnd,
    uint32_t* __restrict__ z)
{
    __shared__ __align__(16) uint32_t WLu[8192];           // 32 KB packed fp16 weights
    __shared__ __align__(16) float As[NG][2][10][10];      // 6.4 KB norm. adj
    __shared__ float rsv[NG][2][10];                       // 640 B
    __shared__ __align__(16) uint32_t Xsu[NG][10][64];     // 20 KB X; reused as Us
    __shared__ __align__(16) uint32_t H16a[NG][10][16][2]; // 10 KB (ping)
    __shared__ __align__(16) uint32_t H16b[NG][10][16][2]; // 10 KB (pong); first reused as Ys
    // total = 80,768 B -> 2 blocks/CU

    const int tid = threadIdx.x;
    const int bt0 = blockIdx.x * NG;
    const int g  = (tid >> 6) & 7;   // wave-uniform graph
    const int ih = tid >> 9;         // wave-uniform row-half (rows ih*5 .. ih*5+4)
    const int s  = (tid >> 5) & 1;   // sign
    const int k  = tid & 31;         // output column
    const int i0 = ih * 5;

    // ---- stage base weights packed fp16: [tb][d2g][s*32+k][j] ----
    for (int e = tid; e < 8192; e += 1024) {
        int tb = e >> 12;
        int r = e & 4095;
        int d2g = r >> 8;
        int r2 = r & 255;
        int ln = r2 >> 2;
        int j  = r2 & 3;
        int ss = ln >> 5, kk = ln & 31;
        int d2 = d2g * 4 + j;
        const float* Ws = (ss ? Wnb : Wpb) + (tb * 128 + 2 * d2) * 32 + kk;
        WLu[e] = pkh2(Ws[0], Ws[32]);
    }
    // ---- stage X packed fp16 ----
    for (int e = tid; e < NG * 640; e += 1024) {
        int gg = e / 640, r = e - gg * 640;
        const float2* xp = reinterpret_cast<const float2*>(
            x + (size_t)(bt0 + gg) * 1280);
        float2 v = xp[r];
        (&Xsu[0][0][0])[e] = pkh2(v.x, v.y);
    }
    // ---- load raw adjacencies ----
    for (int e = tid; e < NG * 200; e += 1024) {
        int gg = e / 200, r = e - gg * 200;
        int sg = r / 100, rr = r - sg * 100;
        (&As[gg][sg][0][0])[rr] =
            (sg ? A_neg : A_pos)[(size_t)(bt0 + gg) * 100 + rr];
    }
    __syncthreads();
    if (tid < NG * 20) {
        int gg = tid / 20, r = tid % 20, sg = r / 10, i = r % 10;
        float sum = 0.f;
        #pragma unroll
        for (int j = 0; j < 10; ++j) sum += As[gg][sg][i][j];
        rsv[gg][sg][i] = 1.0f / (sum + 1e-8f);
    }
    __syncthreads();
    for (int e = tid; e < NG * 200; e += 1024) {
        int gg = e / 200, r = e - gg * 200;
        int sg = r / 100, rr = r - sg * 100;
        As[gg][sg][rr / 10][rr % 10] *= rsv[gg][sg][rr / 10];
    }
    __syncthreads();

    // per-thread packed output slot: u16 index (i stride 64)
    const int hslot = g * 640 + (k >> 1) * 4 + s * 2 + (k & 1);
    uint16_t* Ys = reinterpret_cast<uint16_t*>(&H16b[0][0][0][0]); // [g][s][j][k] u16
    uint32_t* Us = &Xsu[0][0][0];                                  // [g][s][j][k] u32

    // ---- base layer: accY/accZ for my 5 rows; Y exchanged via Ys ----
    float accZ[5];
    {
        float accY[5];
        #pragma unroll
        for (int r = 0; r < 5; ++r) { accY[r] = 0.f; accZ[r] = 0.f; }
        const uint32_t* Wt = &WLu[(s * 32 + k) * 4];
        const uint32_t* Xg = &Xsu[g][0][0];
        for (int d2g = 0; d2g < 16; ++d2g) {
            uint4 wt = *reinterpret_cast<const uint4*>(Wt + d2g * 256);
            uint4 wb = *reinterpret_cast<const uint4*>(Wt + 4096 + d2g * 256);
            #pragma unroll
            for (int r = 0; r < 5; ++r) {
                uint4 xv = *reinterpret_cast<const uint4*>(Xg + (i0 + r) * 64 + d2g * 4);
                accY[r] = dot2(xv.x, wt.x, accY[r]);
                accY[r] = dot2(xv.y, wt.y, accY[r]);
                accY[r] = dot2(xv.z, wt.z, accY[r]);
                accY[r] = dot2(xv.w, wt.w, accY[r]);
                accZ[r] = dot2(xv.x, wb.x, accZ[r]);
                accZ[r] = dot2(xv.y, wb.y, accZ[r]);
                accZ[r] = dot2(xv.z, wb.z, accZ[r]);
                accZ[r] = dot2(xv.w, wb.w, accZ[r]);
            }
        }
        #pragma unroll
        for (int r = 0; r < 5; ++r)
            Ys[((g * 2 + s) * 10 + i0 + r) * 32 + k] = f2h(accY[r]);
    }
    __syncthreads();
    {
        float Yv[10];
        const uint16_t* Yc = Ys + (g * 2 + s) * 320 + k;
        #pragma unroll
        for (int j = 0; j < 10; ++j) Yv[j] = h2f(Yc[j * 32]);
        float bb = (s ? bnb : bpb)[k];
        uint16_t* Hw = reinterpret_cast<uint16_t*>(&H16a[0][0][0][0]);
        const float2* Ar = reinterpret_cast<const float2*>(&As[g][s][0][0]);
        #pragma unroll
        for (int r = 0; r < 5; ++r) {
            int i = i0 + r;
            float acc = accZ[r] + bb;
            #pragma unroll
            for (int m = 0; m < 5; ++m) {
                float2 a2 = Ar[i * 5 + m];
                acc += a2.x * Yv[2 * m] + a2.y * Yv[2 * m + 1];
            }
            Hw[hslot + i * 64] = f2h(fast_tanh(acc));
        }
    }
    __syncthreads();

    // ---- two deep layers: my 5 source rows; U12/U34 exchanged via Us ----
    for (int l = 0; l < 2; ++l) {
        // restage deep weights packed fp16: [blk][cpg][s*32+k][j]
        for (int e = tid; e < 6144; e += 1024) {
            int blk = e >> 10;
            int r = e & 1023;
            int cpg = r >> 8;
            int r2 = r & 255;
            int ln = r2 >> 2;
            int j = r2 & 3;
            int ss = ln >> 5, kk = ln & 31;
            int cp = cpg * 4 + j;
            const float* Ws = (ss ? Wnd : Wpd) + l * 7168;
            int rk = blk * 32 + 2 * cp;
            float f0 = Ws[rk * 32 + kk];
            float f1 = Ws[(rk + 1) * 32 + kk];
            if (blk >= 4 && ((blk == 4) == (ss == 0))) {
                f0 += Ws[(192 + 2 * cp) * 32 + kk];
                f1 += Ws[(193 + 2 * cp) * 32 + kk];
            }
            WLu[e] = pkh2(f0, f1);
        }
        __syncthreads();

        const uint32_t* Hin = l ? &H16b[0][0][0][0] : &H16a[0][0][0][0];
        uint16_t* Hout16 = reinterpret_cast<uint16_t*>(
            l ? &H16a[0][0][0][0] : &H16b[0][0][0][0]);
        const uint32_t* Wd = &WLu[(s * 32 + k) * 4];
        const uint32_t* Hg = Hin + g * 320;

        float U12[5], U34[5], Dd[5];
        #pragma unroll
        for (int r = 0; r < 5; ++r) { U12[r] = 0.f; U34[r] = 0.f; Dd[r] = 0.f; }

        // pass 1: U12 (blocks 0,1) — low register liveness
        for (int cpg = 0; cpg < 4; ++cpg) {
            uint4 w0 = *reinterpret_cast<const uint4*>(Wd + 0 * 1024 + cpg * 256);
            uint4 w1 = *reinterpret_cast<const uint4*>(Wd + 1 * 1024 + cpg * 256);
            #pragma unroll
            for (int r = 0; r < 5; ++r) {
                const uint32_t* hj = Hg + (i0 + r) * 32 + cpg * 8;
                uint4 ha = *reinterpret_cast<const uint4*>(hj);
                uint4 hb = *reinterpret_cast<const uint4*>(hj + 4);
                U12[r] = dot2(ha.x, w0.x, U12[r]);
                U12[r] = dot2(ha.z, w0.y, U12[r]);
                U12[r] = dot2(hb.x, w0.z, U12[r]);
                U12[r] = dot2(hb.z, w0.w, U12[r]);
                U12[r] = dot2(ha.y, w1.x, U12[r]);
                U12[r] = dot2(ha.w, w1.y, U12[r]);
                U12[r] = dot2(hb.y, w1.z, U12[r]);
                U12[r] = dot2(hb.w, w1.w, U12[r]);
            }
        }
        // pass 2: U34 (blocks 2,3) + Dd (blocks 4,5)
        for (int cpg = 0; cpg < 4; ++cpg) {
            uint4 w2 = *reinterpret_cast<const uint4*>(Wd + 2 * 1024 + cpg * 256);
            uint4 w3 = *reinterpret_cast<const uint4*>(Wd + 3 * 1024 + cpg * 256);
            uint4 w4 = *reinterpret_cast<const uint4*>(Wd + 4 * 1024 + cpg * 256);
            uint4 w5 = *reinterpret_cast<const uint4*>(Wd + 5 * 1024 + cpg * 256);
            #pragma unroll
            for (int r = 0; r < 5; ++r) {
                const uint32_t* hj = Hg + (i0 + r) * 32 + cpg * 8;
                uint4 ha = *reinterpret_cast<const uint4*>(hj);
                uint4 hb = *reinterpret_cast<const uint4*>(hj + 4);
                U34[r] = dot2(ha.x, w2.x, U34[r]);
                U34[r] = dot2(ha.z, w2.y, U34[r]);
                U34[r] = dot2(hb.x, w2.z, U34[r]);
                U34[r] = dot2(hb.z, w2.w, U34[r]);
                U34[r] = dot2(ha.y, w3.x, U34[r]);
                U34[r] = dot2(ha.w, w3.y, U34[r]);
                U34[r] = dot2(hb.y, w3.z, U34[r]);
                U34[r] = dot2(hb.w, w3.w, U34[r]);
                Dd[r]  = dot2(ha.x, w4.x, Dd[r]);
                Dd[r]  = dot2(ha.z, w4.y, Dd[r]);
                Dd[r]  = dot2(hb.x, w4.z, Dd[r]);
                Dd[r]  = dot2(hb.z, w4.w, Dd[r]);
                Dd[r]  = dot2(ha.y, w5.x, Dd[r]);
                Dd[r]  = dot2(ha.w, w5.y, Dd[r]);
                Dd[r]  = dot2(hb.y, w5.z, Dd[r]);
                Dd[r]  = dot2(hb.w, w5.w, Dd[r]);
            }
        }
        #pragma unroll
        for (int r = 0; r < 5; ++r)
            Us[((g * 2 + s) * 10 + i0 + r) * 32 + k] = pkh2(U12[r], U34[r]);
        __syncthreads();

        {
            float U1v[10], U3v[10];
            const uint32_t* Uc = Us + (g * 2 + s) * 320 + k;
            #pragma unroll
            for (int j = 0; j < 10; ++j) {
                float2 u = up2(Uc[j * 32]);
                U1v[j] = u.x; U3v[j] = u.y;
            }
            float bb = (s ? bnd : bpd)[l * 32 + k];
            const float2* Ap = reinterpret_cast<const float2*>(&As[g][0][0][0]);
            const float2* An = reinterpret_cast<const float2*>(&As[g][1][0][0]);
            #pragma unroll
            for (int r = 0; r < 5; ++r) {
                int i = i0 + r;
                float acc = Dd[r] + bb;
                #pragma unroll
                for (int m = 0; m < 5; ++m) {
                    float2 ap = Ap[i * 5 + m], an = An[i * 5 + m];
                    acc += ap.x * U1v[2 * m] + ap.y * U1v[2 * m + 1]
                         + an.x * U3v[2 * m] + an.y * U3v[2 * m + 1];
                }
                Hout16[hslot + i * 64] = f2h(fast_tanh(acc));
            }
        }
        __syncthreads();
    }

    // ---- z = cat([h_pos, h_neg], -1) as packed fp16 u32 (final H in H16a) ----
    {
        uint32_t* zb = z + (size_t)bt0 * 320;
        const uint32_t* Hf = &H16a[0][0][0][0];
        for (int e = tid; e < NG * 320; e += 1024) {
            int gg = e / 320, r = e - gg * 320;
            int i = r >> 5, m = r & 31;
            zb[e] = Hf[gg * 320 + i * 32 + (m & 15) * 2 + (m >> 4)];
        }
    }
}

// ---------------------------------------------------------------------------
// LSTM v6: 4 games/block (640 blocks). lstm is barrier/latency-bound, so
// amortize the fixed per-step cost over 2x work: 256 dot2/thread/step, all
// 256 threads active in the activation phase (was 128). Same 2-barrier
// structure; z[t+1] LDS-write + z[t+2] global prefetch overlapped with
// activation. Weights stay packed fp16 in 64 VGPRs.
// ---------------------------------------------------------------------------
__global__ __launch_bounds__(256) void lstm_kernel(
    const uint32_t* __restrict__ zin,
    const float* __restrict__ W_ih,
    const float* __restrict__ W_hh,
    const float* __restrict__ b_ih,
    const float* __restrict__ b_hh,
    float* __restrict__ out)
{
    __shared__ __align__(16) uint32_t zh[GL][64];  // per game: [z 32 u32 | h 32 u32] fp16
    __shared__ float gbuf[GL][256];                // gate pre-activations fp32

    const int tid = threadIdx.x;
    const int p   = blockIdx.x % 10;
    const int b0  = (blockIdx.x / 10) * GL;

    uint32_t wreg[64];   // packed fp16: [z-pairs 0..31 | h-pairs 32..63]
    {
        const float4* wi4 = reinterpret_cast<const float4*>(
            W_ih + ((size_t)p * 256 + tid) * 64);
        const float4* wh4 = reinterpret_cast<const float4*>(
            W_hh + ((size_t)p * 256 + tid) * 64);
        #pragma unroll
        for (int m = 0; m < 16; ++m) {
            float4 v = wi4[m];
            wreg[m * 2 + 0] = pkh2(v.x, v.y);
            wreg[m * 2 + 1] = pkh2(v.z, v.w);
        }
        #pragma unroll
        for (int m = 0; m < 16; ++m) {
            float4 v = wh4[m];
            wreg[32 + m * 2 + 0] = pkh2(v.x, v.y);
            wreg[32 + m * 2 + 1] = pkh2(v.z, v.w);
        }
    }
    const float bias = b_ih[p * 256 + tid] + b_hh[p * 256 + tid];
    const int n = tid >> 6, kk = tid & 63;   // activation roles (all threads)
    const int ln = tid >> 5, lk = tid & 31;  // z-stager roles (tid < 128)
    float creg = 0.f;
    uint32_t znext = 0;

    if (tid < 128) {
        zh[ln][32 + lk] = 0u;                                       // h := 0
        zh[ln][lk] = zin[((size_t)(b0 + ln) * 64 + 0) * 320 + p * 32 + lk];  // z[0]
        znext      = zin[((size_t)(b0 + ln) * 64 + 1) * 320 + p * 32 + lk];  // z[1]
    }
    __syncthreads();

    for (int t = 0; t < 64; ++t) {
        // phase B: thread computes gate row tid for all 4 games (8 chains)
        float a0[GL], a1[GL];
        #pragma unroll
        for (int gm = 0; gm < GL; ++gm) { a0[gm] = bias; a1[gm] = 0.f; }
        #pragma unroll
        for (int q = 0; q < 16; ++q) {
            #pragma unroll
            for (int gm = 0; gm < GL; ++gm) {
                uint4 zv = *reinterpret_cast<const uint4*>(&zh[gm][q * 4]);
                a0[gm] = dot2(zv.x, wreg[q * 4 + 0], a0[gm]);
                a1[gm] = dot2(zv.y, wreg[q * 4 + 1], a1[gm]);
                a0[gm] = dot2(zv.z, wreg[q * 4 + 2], a0[gm]);
                a1[gm] = dot2(zv.w, wreg[q * 4 + 3], a1[gm]);
            }
        }
        #pragma unroll
        for (int gm = 0; gm < GL; ++gm) gbuf[gm][tid] = a0[gm] + a1[gm];
        __syncthreads();

        // phase A: z[t+1] LDS write, activation (all 256), z[t+2] prefetch
        if (tid < 128 && t < 63) zh[ln][lk] = znext;
        {
            float gi = gbuf[n][kk];
            float gf = gbuf[n][64 + kk];
            float gg = gbuf[n][128 + kk];
            float go = gbuf[n][192 + kk];
            float cn = sigmoidf_(gf) * creg + sigmoidf_(gi) * fast_tanh(gg);
            float hn = sigmoidf_(go) * fast_tanh(cn);
            creg = cn;
            reinterpret_cast<uint16_t*>(&zh[0][0])[n * 128 + 64 + kk] = f2h(hn);
            out[((size_t)(b0 + n) * 64 + t) * 640 + p * 64 + kk] = hn;
        }
        if (tid < 128 && t < 62)
            znext = zin[((size_t)(b0 + ln) * 64 + t + 2) * 320 + p * 32 + lk];
        __syncthreads();
    }
}

extern "C" void kernel_launch(void* const* d_in, const int* in_sizes, int n_in,
                              void* d_out, int out_size, void* d_ws, size_t ws_size,
                              hipStream_t stream) {
    const float* x     = (const float*)d_in[0];
    const float* A_pos = (const float*)d_in[1];
    const float* A_neg = (const float*)d_in[2];
    const float* Wpb   = (const float*)d_in[3];
    const float* bpb   = (const float*)d_in[4];
    const float* Wnb   = (const float*)d_in[5];
    const float* bnb   = (const float*)d_in[6];
    const float* Wpd   = (const float*)d_in[7];
    const float* bpd   = (const float*)d_in[8];
    const float* Wnd   = (const float*)d_in[9];
    const float* bnd   = (const float*)d_in[10];
    const float* Wih   = (const float*)d_in[11];
    const float* Whh   = (const float*)d_in[12];
    const float* bih   = (const float*)d_in[13];
    const float* bhh   = (const float*)d_in[14];

    uint32_t* z = (uint32_t*)d_ws;     // [B,T,P,32] packed fp16 pairs = 20 MB
    float* out  = (float*)d_out;       // [B,T,P,64] fp32 = 40 MB

    sgcn_kernel<<<(Bg * Tg) / NG, 1024, 0, stream>>>(
        x, A_pos, A_neg, Wpb, bpb, Wnb, bnb, Wpd, bpd, Wnd, bnd, z);
    lstm_kernel<<<(Bg / GL) * Pg, 256, 0, stream>>>(
        z, Wih, Whh, bih, bhh, out);
}

// Round 4
// 523.827 us; speedup vs baseline: 1.3151x; 1.3151x over previous
//
#include <hip/hip_runtime.h>
#include <stdint.h>

// Problem dims
#define Bg 256
#define Tg 64
#define Pg 10
#define NG 4   // graphs per sgcn block
#define GL 4   // lstm games per block

typedef _Float16 half2v __attribute__((ext_vector_type(2)));
typedef _Float16 f16x8 __attribute__((ext_vector_type(8)));
typedef float f32x4v __attribute__((ext_vector_type(4)));

// fp16 packed dot product with fp32 accumulate: c + a.x*b.x + a.y*b.y
__device__ __forceinline__ float dot2(uint32_t a, uint32_t b, float c) {
#if __has_builtin(__builtin_amdgcn_fdot2)
    return __builtin_amdgcn_fdot2(__builtin_bit_cast(half2v, a),
                                  __builtin_bit_cast(half2v, b), c, false);
#else
    float d;
    asm("v_dot2_f32_f16 %0, %1, %2, %3"
        : "=v"(d) : "v"(a), "v"(b), "v"(c));
    return d;
#endif
}

__device__ __forceinline__ uint32_t pkh2(float lo, float hi) {
    half2v h; h.x = (_Float16)lo; h.y = (_Float16)hi;
    return __builtin_bit_cast(uint32_t, h);
}
__device__ __forceinline__ uint16_t f2h(float f) {
    _Float16 h = (_Float16)f;
    return __builtin_bit_cast(uint16_t, h);
}
__device__ __forceinline__ float h2f(uint16_t u) {
    _Float16 h = __builtin_bit_cast(_Float16, u);
    return (float)h;
}
__device__ __forceinline__ float2 up2(uint32_t u) {
    half2v h = __builtin_bit_cast(half2v, u);
    return make_float2((float)h.x, (float)h.y);
}
__device__ __forceinline__ float sigmoidf_(float x) {
    return 1.0f / (1.0f + __expf(-x));
}
__device__ __forceinline__ float fast_tanh(float x) {
    float e = __expf(2.0f * x);
    return (e - 1.0f) / (e + 1.0f);
}

// ---------------------------------------------------------------------------
// SGCN v7: NG=4, 512 threads, 5 rows/thread (row-half split ih), WLu 16 KB
// (base weights staged in two d-halves; deep weights in two block-groups).
// LDS = 40.4 KB -> 4 blocks/CU = 32 waves = 100% occupancy. NO min-wave
// launch bound (r3 lesson: (1024,8) cap -> spills -> 822 MB scratch writes).
// ---------------------------------------------------------------------------
__global__ __launch_bounds__(512) void sgcn_kernel(
    const float* __restrict__ x,
    const float* __restrict__ A_pos,
    const float* __restrict__ A_neg,
    const float* __restrict__ Wpb,
    const float* __restrict__ bpb,
    const float* __restrict__ Wnb,
    const float* __restrict__ bnb,
    const float* __restrict__ Wpd,
    const float* __restrict__ bpd,
    const float* __restrict__ Wnd,
    const float* __restrict__ bnd,
    uint32_t* __restrict__ z)
{
    __shared__ __align__(16) uint32_t WLu[4096];           // 16 KB packed fp16 weights
    __shared__ __align__(16) float As[NG][2][10][10];      // 3.2 KB
    __shared__ float rsv[NG][2][10];                       // 320 B
    __shared__ __align__(16) uint32_t Xsu[NG][10][64];     // 10 KB X; reused as Us
    __shared__ __align__(16) uint32_t H16a[NG][10][16][2]; // 5 KB (ping)
    __shared__ __align__(16) uint32_t H16b[NG][10][16][2]; // 5 KB (pong); first Ys
    // total = 40,384 B -> 4 blocks/CU

    const int tid = threadIdx.x;
    const int bt0 = blockIdx.x * NG;
    const int g  = tid >> 7;         // wave-uniform graph (128 thr/graph)
    const int ih = (tid >> 6) & 1;   // wave-uniform row half
    const int s  = (tid >> 5) & 1;   // sign
    const int k  = tid & 31;         // output column
    const int i0 = ih * 5;

    // ---- prologue staging: base weights pass1 (d2 0..31), X, adjacencies ----
    for (int e = tid; e < 4096; e += 512) {
        int tb = e >> 11, r = e & 2047;
        int d2g = r >> 8, r2 = r & 255;
        int ln = r2 >> 2, j = r2 & 3;
        int ss = ln >> 5, kk = ln & 31;
        int d2 = d2g * 4 + j;
        const float* Ws = (ss ? Wnb : Wpb) + (tb * 128 + 2 * d2) * 32 + kk;
        WLu[e] = pkh2(Ws[0], Ws[32]);
    }
    for (int e = tid; e < NG * 640; e += 512) {
        int gg = e / 640, r = e - gg * 640;
        const float2* xp = reinterpret_cast<const float2*>(
            x + (size_t)(bt0 + gg) * 1280);
        float2 v = xp[r];
        (&Xsu[0][0][0])[e] = pkh2(v.x, v.y);
    }
    for (int e = tid; e < NG * 200; e += 512) {
        int gg = e / 200, r = e - gg * 200;
        int sg = r / 100, rr = r - sg * 100;
        (&As[gg][sg][0][0])[rr] =
            (sg ? A_neg : A_pos)[(size_t)(bt0 + gg) * 100 + rr];
    }
    __syncthreads();
    if (tid < NG * 20) {
        int gg = tid / 20, r = tid % 20, sg = r / 10, i = r % 10;
        float sum = 0.f;
        #pragma unroll
        for (int j = 0; j < 10; ++j) sum += As[gg][sg][i][j];
        rsv[gg][sg][i] = 1.0f / (sum + 1e-8f);
    }
    __syncthreads();
    for (int e = tid; e < NG * 200; e += 512) {
        int gg = e / 200, r = e - gg * 200;
        int sg = r / 100, rr = r - sg * 100;
        As[gg][sg][rr / 10][rr % 10] *= rsv[gg][sg][rr / 10];
    }
    __syncthreads();

    const int hslot = g * 640 + (k >> 1) * 4 + s * 2 + (k & 1);
    uint16_t* Ys = reinterpret_cast<uint16_t*>(&H16b[0][0][0][0]);
    uint32_t* Us = &Xsu[0][0][0];

    // ---- base layer: 2 weight passes over d; Y exchanged via Ys ----
    float accY[5], accZ[5];
    #pragma unroll
    for (int r = 0; r < 5; ++r) { accY[r] = 0.f; accZ[r] = 0.f; }
    {
        const uint32_t* Wt = &WLu[(s * 32 + k) * 4];
        const uint32_t* Xg = &Xsu[g][0][0];
        for (int d2g = 0; d2g < 8; ++d2g) {
            uint4 wt = *reinterpret_cast<const uint4*>(Wt + d2g * 256);
            uint4 wb = *reinterpret_cast<const uint4*>(Wt + 2048 + d2g * 256);
            #pragma unroll
            for (int r = 0; r < 5; ++r) {
                uint4 xv = *reinterpret_cast<const uint4*>(Xg + (i0 + r) * 64 + d2g * 4);
                accY[r] = dot2(xv.x, wt.x, accY[r]);
                accY[r] = dot2(xv.y, wt.y, accY[r]);
                accY[r] = dot2(xv.z, wt.z, accY[r]);
                accY[r] = dot2(xv.w, wt.w, accY[r]);
                accZ[r] = dot2(xv.x, wb.x, accZ[r]);
                accZ[r] = dot2(xv.y, wb.y, accZ[r]);
                accZ[r] = dot2(xv.z, wb.z, accZ[r]);
                accZ[r] = dot2(xv.w, wb.w, accZ[r]);
            }
        }
    }
    __syncthreads();
    // stage base pass2 (d2 32..63)
    for (int e = tid; e < 4096; e += 512) {
        int tb = e >> 11, r = e & 2047;
        int d2g = r >> 8, r2 = r & 255;
        int ln = r2 >> 2, j = r2 & 3;
        int ss = ln >> 5, kk = ln & 31;
        int d2 = 32 + d2g * 4 + j;
        const float* Ws = (ss ? Wnb : Wpb) + (tb * 128 + 2 * d2) * 32 + kk;
        WLu[e] = pkh2(Ws[0], Ws[32]);
    }
    __syncthreads();
    {
        const uint32_t* Wt = &WLu[(s * 32 + k) * 4];
        const uint32_t* Xg = &Xsu[g][0][0];
        for (int d2g = 0; d2g < 8; ++d2g) {
            uint4 wt = *reinterpret_cast<const uint4*>(Wt + d2g * 256);
            uint4 wb = *reinterpret_cast<const uint4*>(Wt + 2048 + d2g * 256);
            #pragma unroll
            for (int r = 0; r < 5; ++r) {
                uint4 xv = *reinterpret_cast<const uint4*>(Xg + (i0 + r) * 64 + 32 + d2g * 4);
                accY[r] = dot2(xv.x, wt.x, accY[r]);
                accY[r] = dot2(xv.y, wt.y, accY[r]);
                accY[r] = dot2(xv.z, wt.z, accY[r]);
                accY[r] = dot2(xv.w, wt.w, accY[r]);
                accZ[r] = dot2(xv.x, wb.x, accZ[r]);
                accZ[r] = dot2(xv.y, wb.y, accZ[r]);
                accZ[r] = dot2(xv.z, wb.z, accZ[r]);
                accZ[r] = dot2(xv.w, wb.w, accZ[r]);
            }
        }
        #pragma unroll
        for (int r = 0; r < 5; ++r)
            Ys[((g * 2 + s) * 10 + i0 + r) * 32 + k] = f2h(accY[r]);
    }
    __syncthreads();
    {
        float Yv[10];
        const uint16_t* Yc = Ys + (g * 2 + s) * 320 + k;
        #pragma unroll
        for (int j = 0; j < 10; ++j) Yv[j] = h2f(Yc[j * 32]);
        float bb = (s ? bnb : bpb)[k];
        uint16_t* Hw = reinterpret_cast<uint16_t*>(&H16a[0][0][0][0]);
        const float2* Ar = reinterpret_cast<const float2*>(&As[g][s][0][0]);
        #pragma unroll
        for (int r = 0; r < 5; ++r) {
            int i = i0 + r;
            float acc = accZ[r] + bb;
            #pragma unroll
            for (int m = 0; m < 5; ++m) {
                float2 a2 = Ar[i * 5 + m];
                acc += a2.x * Yv[2 * m] + a2.y * Yv[2 * m + 1];
            }
            Hw[hslot + i * 64] = f2h(fast_tanh(acc));
        }
    }
    __syncthreads();

    // ---- two deep layers: 2 weight passes per layer; U exchanged via Us ----
    for (int l = 0; l < 2; ++l) {
        // stage pass A: blocks 0,1
        for (int e = tid; e < 2048; e += 512) {
            int blk = e >> 10, cpg = (e >> 8) & 3;
            int ln = (e >> 2) & 63, j = e & 3;
            int ss = ln >> 5, kk = ln & 31, cp = cpg * 4 + j;
            const float* Ws = (ss ? Wnd : Wpd) + l * 7168;
            int rk = blk * 32 + 2 * cp;
            WLu[e] = pkh2(Ws[rk * 32 + kk], Ws[(rk + 1) * 32 + kk]);
        }
        __syncthreads();

        const uint32_t* Hin = l ? &H16b[0][0][0][0] : &H16a[0][0][0][0];
        uint16_t* Hout16 = reinterpret_cast<uint16_t*>(
            l ? &H16a[0][0][0][0] : &H16b[0][0][0][0]);
        const uint32_t* Wd = &WLu[(s * 32 + k) * 4];
        const uint32_t* Hg = Hin + g * 320;

        float U12[5], U34[5], Dd[5];
        #pragma unroll
        for (int r = 0; r < 5; ++r) { U12[r] = 0.f; U34[r] = 0.f; Dd[r] = 0.f; }

        for (int cpg = 0; cpg < 4; ++cpg) {
            uint4 w0 = *reinterpret_cast<const uint4*>(Wd + cpg * 256);
            uint4 w1 = *reinterpret_cast<const uint4*>(Wd + 1024 + cpg * 256);
            #pragma unroll
            for (int r = 0; r < 5; ++r) {
                const uint32_t* hj = Hg + (i0 + r) * 32 + cpg * 8;
                uint4 ha = *reinterpret_cast<const uint4*>(hj);
                uint4 hb = *reinterpret_cast<const uint4*>(hj + 4);
                U12[r] = dot2(ha.x, w0.x, U12[r]);
                U12[r] = dot2(ha.z, w0.y, U12[r]);
                U12[r] = dot2(hb.x, w0.z, U12[r]);
                U12[r] = dot2(hb.z, w0.w, U12[r]);
                U12[r] = dot2(ha.y, w1.x, U12[r]);
                U12[r] = dot2(ha.w, w1.y, U12[r]);
                U12[r] = dot2(hb.y, w1.z, U12[r]);
                U12[r] = dot2(hb.w, w1.w, U12[r]);
            }
        }
        __syncthreads();
        // stage pass B: blocks 2..5 (self-block w7 pre-merged)
        for (int e = tid; e < 4096; e += 512) {
            int blk = 2 + (e >> 10), cpg = (e >> 8) & 3;
            int ln = (e >> 2) & 63, j = e & 3;
            int ss = ln >> 5, kk = ln & 31, cp = cpg * 4 + j;
            const float* Ws = (ss ? Wnd : Wpd) + l * 7168;
            int rk = blk * 32 + 2 * cp;
            float f0 = Ws[rk * 32 + kk];
            float f1 = Ws[(rk + 1) * 32 + kk];
            if (blk >= 4 && ((blk == 4) == (ss == 0))) {
                f0 += Ws[(192 + 2 * cp) * 32 + kk];
                f1 += Ws[(193 + 2 * cp) * 32 + kk];
            }
            WLu[e] = pkh2(f0, f1);
        }
        __syncthreads();
        for (int cpg = 0; cpg < 4; ++cpg) {
            uint4 w2 = *reinterpret_cast<const uint4*>(Wd + cpg * 256);
            uint4 w3 = *reinterpret_cast<const uint4*>(Wd + 1024 + cpg * 256);
            uint4 w4 = *reinterpret_cast<const uint4*>(Wd + 2048 + cpg * 256);
            uint4 w5 = *reinterpret_cast<const uint4*>(Wd + 3072 + cpg * 256);
            #pragma unroll
            for (int r = 0; r < 5; ++r) {
                const uint32_t* hj = Hg + (i0 + r) * 32 + cpg * 8;
                uint4 ha = *reinterpret_cast<const uint4*>(hj);
                uint4 hb = *reinterpret_cast<const uint4*>(hj + 4);
                U34[r] = dot2(ha.x, w2.x, U34[r]);
                U34[r] = dot2(ha.z, w2.y, U34[r]);
                U34[r] = dot2(hb.x, w2.z, U34[r]);
                U34[r] = dot2(hb.z, w2.w, U34[r]);
                U34[r] = dot2(ha.y, w3.x, U34[r]);
                U34[r] = dot2(ha.w, w3.y, U34[r]);
                U34[r] = dot2(hb.y, w3.z, U34[r]);
                U34[r] = dot2(hb.w, w3.w, U34[r]);
                Dd[r]  = dot2(ha.x, w4.x, Dd[r]);
                Dd[r]  = dot2(ha.z, w4.y, Dd[r]);
                Dd[r]  = dot2(hb.x, w4.z, Dd[r]);
                Dd[r]  = dot2(hb.z, w4.w, Dd[r]);
                Dd[r]  = dot2(ha.y, w5.x, Dd[r]);
                Dd[r]  = dot2(ha.w, w5.y, Dd[r]);
                Dd[r]  = dot2(hb.y, w5.z, Dd[r]);
                Dd[r]  = dot2(hb.w, w5.w, Dd[r]);
            }
        }
        #pragma unroll
        for (int r = 0; r < 5; ++r)
            Us[((g * 2 + s) * 10 + i0 + r) * 32 + k] = pkh2(U12[r], U34[r]);
        __syncthreads();

        {
            float U1v[10], U3v[10];
            const uint32_t* Uc = Us + (g * 2 + s) * 320 + k;
            #pragma unroll
            for (int j = 0; j < 10; ++j) {
                float2 u = up2(Uc[j * 32]);
                U1v[j] = u.x; U3v[j] = u.y;
            }
            float bb = (s ? bnd : bpd)[l * 32 + k];
            const float2* Ap = reinterpret_cast<const float2*>(&As[g][0][0][0]);
            const float2* An = reinterpret_cast<const float2*>(&As[g][1][0][0]);
            #pragma unroll
            for (int r = 0; r < 5; ++r) {
                int i = i0 + r;
                float acc = Dd[r] + bb;
                #pragma unroll
                for (int m = 0; m < 5; ++m) {
                    float2 ap = Ap[i * 5 + m], an = An[i * 5 + m];
                    acc += ap.x * U1v[2 * m] + ap.y * U1v[2 * m + 1]
                         + an.x * U3v[2 * m] + an.y * U3v[2 * m + 1];
                }
                Hout16[hslot + i * 64] = f2h(fast_tanh(acc));
            }
        }
        __syncthreads();
    }

    // ---- z output (final H in H16a) ----
    {
        uint32_t* zb = z + (size_t)bt0 * 320;
        const uint32_t* Hf = &H16a[0][0][0][0];
        for (int e = tid; e < NG * 320; e += 512) {
            int gg = e / 320, r = e - gg * 320;
            int i = r >> 5, m = r & 31;
            zb[e] = Hf[gg * 320 + i * 32 + (m & 15) * 2 + (m >> 4)];
        }
    }
}

// ---------------------------------------------------------------------------
// LSTM v7 (MFMA): gates[256 x GL] = W[256x128] @ zh[128xGL] per step via
// mfma_f32_16x16x32_f16. W resident as A-frags in 64 VGPRs (step-invariant);
// zh read as B-frags = 4 ds_read_b128/wave/step (was 32 -> the r0-r3 LDS
// bottleneck). k-ordering is permutation-invariant given A/B use the same
// map; cols (games) 4..15 are zero-filled, never read from D.
// Wave w computes gate section w (i,f,g,o). 2 barriers/step.
// ---------------------------------------------------------------------------
__global__ __launch_bounds__(256) void lstm_kernel(
    const uint32_t* __restrict__ zin,
    const float* __restrict__ W_ih,
    const float* __restrict__ W_hh,
    const float* __restrict__ b_ih,
    const float* __restrict__ b_hh,
    float* __restrict__ out)
{
    __shared__ __align__(16) uint32_t Zb[2][4][64][4]; // 8 KB [buf][kt][lane][i]
    __shared__ __align__(16) float gbuf[GL][264];      // 4.1 KB (stride 264: bank-spread)

    const int tid = threadIdx.x;
    const int w   = tid >> 6;        // wave = gate section (i,f,g,o)
    const int l   = tid & 63;        // lane
    const int lg  = l >> 4;          // lane group 0..3 (k-group / row-group)
    const int ln_ = l & 15;          // m (A) / n (B) index within tile
    const int p   = blockIdx.x % 10;
    const int b0  = (blockIdx.x / 10) * GL;

    // ---- A fragments: thread holds W[m][k-slice] for 4 row-tiles x 4 K-steps.
    // lane map: m = w*64 + tt*16 + ln_;  k = kt*32 + lg*8 + (2i, 2i+1)
    f16x8 wfrag[16];
    #pragma unroll
    for (int tt = 0; tt < 4; ++tt) {
        int m = w * 64 + tt * 16 + ln_;
        #pragma unroll
        for (int kt = 0; kt < 4; ++kt) {
            const float* Wsrc = (kt < 2) ? W_ih : W_hh;
            const float* base = Wsrc + ((size_t)p * 256 + m) * 64 + (kt & 1) * 32 + lg * 8;
            float4 v0 = *reinterpret_cast<const float4*>(base);
            float4 v1 = *reinterpret_cast<const float4*>(base + 4);
            f16x8 a;
            a[0] = (_Float16)v0.x; a[1] = (_Float16)v0.y;
            a[2] = (_Float16)v0.z; a[3] = (_Float16)v0.w;
            a[4] = (_Float16)v1.x; a[5] = (_Float16)v1.y;
            a[6] = (_Float16)v1.z; a[7] = (_Float16)v1.w;
            wfrag[tt * 4 + kt] = a;
        }
    }
    // bias folded into accumulator init: bias row m = w*64 + tt*16 + lg*4 + r
    f32x4v bias0, bias1, bias2, bias3;
    #pragma unroll
    for (int r = 0; r < 4; ++r) {
        int mb = w * 64 + lg * 4 + r;
        bias0[r] = b_ih[p * 256 + mb]      + b_hh[p * 256 + mb];
        bias1[r] = b_ih[p * 256 + mb + 16] + b_hh[p * 256 + mb + 16];
        bias2[r] = b_ih[p * 256 + mb + 32] + b_hh[p * 256 + mb + 32];
        bias3[r] = b_ih[p * 256 + mb + 48] + b_hh[p * 256 + mb + 48];
    }

    // ---- init: zero Zb (both buffers -> h(0)=0, unused cols stay 0) ----
    for (int e = tid; e < 2048; e += 256) (&Zb[0][0][0][0])[e] = 0u;
    // staging roles (tid>=128): game sgm, k-pair sj
    const int sgm = (tid >> 5) & 3, sj = tid & 31;
    uint32_t znext = 0;
    if (tid >= 128) {
        uint32_t z0 = zin[((size_t)(b0 + sgm) * 64 + 0) * 320 + p * 32 + sj];
        Zb[0][sj >> 4][((sj >> 2) & 3) * 16 + sgm][sj & 3] = z0;
        znext = zin[((size_t)(b0 + sgm) * 64 + 1) * 320 + p * 32 + sj];
    }
    __syncthreads();

    // activation roles (tid<128): game agm, h-pair ajh (h elems 2*ajh, 2*ajh+1)
    const int agm = tid >> 5, ajh = tid & 31;
    float c0r = 0.f, c1r = 0.f;

    for (int t = 0; t < 64; ++t) {
        const int buf = t & 1;
        // ---- gate phase: 4 B-frag reads + 16 MFMA ----
        uint4 q0 = *reinterpret_cast<const uint4*>(&Zb[buf][0][l][0]);
        uint4 q1 = *reinterpret_cast<const uint4*>(&Zb[buf][1][l][0]);
        uint4 q2 = *reinterpret_cast<const uint4*>(&Zb[buf][2][l][0]);
        uint4 q3 = *reinterpret_cast<const uint4*>(&Zb[buf][3][l][0]);
        f16x8 bf0 = __builtin_bit_cast(f16x8, q0);
        f16x8 bf1 = __builtin_bit_cast(f16x8, q1);
        f16x8 bf2 = __builtin_bit_cast(f16x8, q2);
        f16x8 bf3 = __builtin_bit_cast(f16x8, q3);
        f32x4v a0 = bias0, a1 = bias1, a2 = bias2, a3 = bias3;
        a0 = __builtin_amdgcn_mfma_f32_16x16x32_f16(wfrag[0],  bf0, a0, 0, 0, 0);
        a0 = __builtin_amdgcn_mfma_f32_16x16x32_f16(wfrag[1],  bf1, a0, 0, 0, 0);
        a0 = __builtin_amdgcn_mfma_f32_16x16x32_f16(wfrag[2],  bf2, a0, 0, 0, 0);
        a0 = __builtin_amdgcn_mfma_f32_16x16x32_f16(wfrag[3],  bf3, a0, 0, 0, 0);
        a1 = __builtin_amdgcn_mfma_f32_16x16x32_f16(wfrag[4],  bf0, a1, 0, 0, 0);
        a1 = __builtin_amdgcn_mfma_f32_16x16x32_f16(wfrag[5],  bf1, a1, 0, 0, 0);
        a1 = __builtin_amdgcn_mfma_f32_16x16x32_f16(wfrag[6],  bf2, a1, 0, 0, 0);
        a1 = __builtin_amdgcn_mfma_f32_16x16x32_f16(wfrag[7],  bf3, a1, 0, 0, 0);
        a2 = __builtin_amdgcn_mfma_f32_16x16x32_f16(wfrag[8],  bf0, a2, 0, 0, 0);
        a2 = __builtin_amdgcn_mfma_f32_16x16x32_f16(wfrag[9],  bf1, a2, 0, 0, 0);
        a2 = __builtin_amdgcn_mfma_f32_16x16x32_f16(wfrag[10], bf2, a2, 0, 0, 0);
        a2 = __builtin_amdgcn_mfma_f32_16x16x32_f16(wfrag[11], bf3, a2, 0, 0, 0);
        a3 = __builtin_amdgcn_mfma_f32_16x16x32_f16(wfrag[12], bf0, a3, 0, 0, 0);
        a3 = __builtin_amdgcn_mfma_f32_16x16x32_f16(wfrag[13], bf1, a3, 0, 0, 0);
        a3 = __builtin_amdgcn_mfma_f32_16x16x32_f16(wfrag[14], bf2, a3, 0, 0, 0);
        a3 = __builtin_amdgcn_mfma_f32_16x16x32_f16(wfrag[15], bf3, a3, 0, 0, 0);
        // D layout: row m = w*64 + tt*16 + lg*4 + reg, col n = ln_ (game)
        if (ln_ < GL) {
            *reinterpret_cast<f32x4v*>(&gbuf[ln_][w * 64 +  0 + lg * 4]) = a0;
            *reinterpret_cast<f32x4v*>(&gbuf[ln_][w * 64 + 16 + lg * 4]) = a1;
            *reinterpret_cast<f32x4v*>(&gbuf[ln_][w * 64 + 32 + lg * 4]) = a2;
            *reinterpret_cast<f32x4v*>(&gbuf[ln_][w * 64 + 48 + lg * 4]) = a3;
        }
        __syncthreads();

        // ---- act phase: tid<128 activation || tid>=128 z[t+1] staging ----
        if (tid < 128) {
            float2 gi = *reinterpret_cast<const float2*>(&gbuf[agm][  0 + 2 * ajh]);
            float2 gf = *reinterpret_cast<const float2*>(&gbuf[agm][ 64 + 2 * ajh]);
            float2 gg = *reinterpret_cast<const float2*>(&gbuf[agm][128 + 2 * ajh]);
            float2 go = *reinterpret_cast<const float2*>(&gbuf[agm][192 + 2 * ajh]);
            float c0 = sigmoidf_(gf.x) * c0r + sigmoidf_(gi.x) * fast_tanh(gg.x);
            float c1 = sigmoidf_(gf.y) * c1r + sigmoidf_(gi.y) * fast_tanh(gg.y);
            float h0 = sigmoidf_(go.x) * fast_tanh(c0);
            float h1 = sigmoidf_(go.y) * fast_tanh(c1);
            c0r = c0; c1r = c1;
            int jp = 32 + ajh;   // k-pair index of h pair
            Zb[buf ^ 1][jp >> 4][((jp >> 2) & 3) * 16 + agm][jp & 3] = pkh2(h0, h1);
            *reinterpret_cast<float2*>(
                &out[((size_t)(b0 + agm) * 64 + t) * 640 + p * 64 + 2 * ajh]) =
                make_float2(h0, h1);
        } else if (t < 63) {
            Zb[buf ^ 1][sj >> 4][((sj >> 2) & 3) * 16 + sgm][sj & 3] = znext;
            if (t < 62)
                znext = zin[((size_t)(b0 + sgm) * 64 + t + 2) * 320 + p * 32 + sj];
        }
        __syncthreads();
    }
}

extern "C" void kernel_launch(void* const* d_in, const int* in_sizes, int n_in,
                              void* d_out, int out_size, void* d_ws, size_t ws_size,
                              hipStream_t stream) {
    const float* x     = (const float*)d_in[0];
    const float* A_pos = (const float*)d_in[1];
    const float* A_neg = (const float*)d_in[2];
    const float* Wpb   = (const float*)d_in[3];
    const float* bpb   = (const float*)d_in[4];
    const float* Wnb   = (const float*)d_in[5];
    const float* bnb   = (const float*)d_in[6];
    const float* Wpd   = (const float*)d_in[7];
    const float* bpd   = (const float*)d_in[8];
    const float* Wnd   = (const float*)d_in[9];
    const float* bnd   = (const float*)d_in[10];
    const float* Wih   = (const float*)d_in[11];
    const float* Whh   = (const float*)d_in[12];
    const float* bih   = (const float*)d_in[13];
    const float* bhh   = (const float*)d_in[14];

    uint32_t* z = (uint32_t*)d_ws;     // [B,T,P,32] packed fp16 pairs = 20 MB
    float* out  = (float*)d_out;       // [B,T,P,64] fp32 = 40 MB

    sgcn_kernel<<<(Bg * Tg) / NG, 512, 0, stream>>>(
        x, A_pos, A_neg, Wpb, bpb, Wnb, bnb, Wpd, bpd, Wnd, bnd, z);
    lstm_kernel<<<(Bg / GL) * Pg, 256, 0, stream>>>(
        z, Wih, Whh, bih, bhh, out);
}

// Round 6
// 468.210 us; speedup vs baseline: 1.4714x; 1.1188x over previous
//
#include <hip/hip_runtime.h>
#include <stdint.h>

// Problem dims
#define Bg 256
#define Tg 64
#define Pg 10
#define NG 8   // graphs per sgcn block
#define GL 4   // lstm games per block

typedef _Float16 half2v __attribute__((ext_vector_type(2)));
typedef _Float16 f16x8 __attribute__((ext_vector_type(8)));
typedef float f32x4v __attribute__((ext_vector_type(4)));

// fp16 packed dot product with fp32 accumulate: c + a.x*b.x + a.y*b.y
__device__ __forceinline__ float dot2(uint32_t a, uint32_t b, float c) {
#if __has_builtin(__builtin_amdgcn_fdot2)
    return __builtin_amdgcn_fdot2(__builtin_bit_cast(half2v, a),
                                  __builtin_bit_cast(half2v, b), c, false);
#else
    float d;
    asm("v_dot2_f32_f16 %0, %1, %2, %3"
        : "=v"(d) : "v"(a), "v"(b), "v"(c));
    return d;
#endif
}

__device__ __forceinline__ uint32_t pkh2(float lo, float hi) {
    half2v h; h.x = (_Float16)lo; h.y = (_Float16)hi;
    return __builtin_bit_cast(uint32_t, h);
}
__device__ __forceinline__ uint16_t f2h(float f) {
    _Float16 h = (_Float16)f;
    return __builtin_bit_cast(uint16_t, h);
}
__device__ __forceinline__ float h2f(uint16_t u) {
    _Float16 h = __builtin_bit_cast(_Float16, u);
    return (float)h;
}
__device__ __forceinline__ float2 up2(uint32_t u) {
    half2v h = __builtin_bit_cast(half2v, u);
    return make_float2((float)h.x, (float)h.y);
}
__device__ __forceinline__ float sigmoidf_(float x) {
    return 1.0f / (1.0f + __expf(-x));
}
__device__ __forceinline__ float fast_tanh(float x) {
    float e = __expf(2.0f * x);
    return (e - 1.0f) / (e + 1.0f);
}

// ---------------------------------------------------------------------------
// SGCN v5 (r2, measured 253 us — best known): fully packed-fp16 + v_dot2
// (base AND deep). NG=8, 512 thr, LDS 80.8 KB -> 2 blocks/CU. One-pass weight
// staging (r4 lesson: splitting staging into more passes to shrink LDS costs
// more in restage+barrier overhead than the occupancy buys back).
// ---------------------------------------------------------------------------
__global__ __launch_bounds__(512) void sgcn_kernel(
    const float* __restrict__ x,
    const float* __restrict__ A_pos,
    const float* __restrict__ A_neg,
    const float* __restrict__ Wpb,
    const float* __restrict__ bpb,
    const float* __restrict__ Wnb,
    const float* __restrict__ bnb,
    const float* __restrict__ Wpd,
    const float* __restrict__ bpd,
    const float* __restrict__ Wnd,
    const float* __restrict__ bnd,
    uint32_t* __restrict__ z)
{
    __shared__ __align__(16) uint32_t WLu[8192];           // 32 KB packed fp16 weights
    __shared__ __align__(16) float As[NG][2][10][10];      // 6.4 KB norm. adj
    __shared__ float rsv[NG][2][10];                       // 640 B
    __shared__ __align__(16) uint32_t Xsu[NG][10][64];     // 20 KB packed fp16 X
    __shared__ __align__(16) uint32_t H16a[NG][10][16][2]; // 10 KB (ping)
    __shared__ __align__(16) uint32_t H16b[NG][10][16][2]; // 10 KB (pong)
    // total = 80,768 B -> 2 blocks/CU

    const int tid = threadIdx.x;
    const int bt0 = blockIdx.x * NG;
    const int g = tid >> 6;          // wave-uniform graph
    const int s = (tid >> 5) & 1;    // sign
    const int k = tid & 31;          // output column

    // ---- stage base weights packed fp16: [tb][d2g][s*32+k][j] ----
    for (int e = tid; e < 8192; e += 512) {
        int tb = e >> 12;
        int r = e & 4095;
        int d2g = r >> 8;
        int r2 = r & 255;
        int ln = r2 >> 2;
        int j  = r2 & 3;
        int ss = ln >> 5, kk = ln & 31;
        int d2 = d2g * 4 + j;
        const float* Ws = (ss ? Wnb : Wpb) + (tb * 128 + 2 * d2) * 32 + kk;
        WLu[e] = pkh2(Ws[0], Ws[32]);
    }
    // ---- stage X packed fp16 ----
    for (int e = tid; e < NG * 640; e += 512) {
        int gg = e / 640, r = e - gg * 640;
        const float2* xp = reinterpret_cast<const float2*>(
            x + (size_t)(bt0 + gg) * 1280);
        float2 v = xp[r];
        (&Xsu[0][0][0])[e] = pkh2(v.x, v.y);
    }
    // ---- load raw adjacencies ----
    for (int e = tid; e < NG * 200; e += 512) {
        int gg = e / 200, r = e - gg * 200;
        int sg = r / 100, rr = r - sg * 100;
        (&As[gg][sg][0][0])[rr] =
            (sg ? A_neg : A_pos)[(size_t)(bt0 + gg) * 100 + rr];
    }
    __syncthreads();
    if (tid < NG * 20) {
        int gg = tid / 20, r = tid % 20, sg = r / 10, i = r % 10;
        float sum = 0.f;
        #pragma unroll
        for (int j = 0; j < 10; ++j) sum += As[gg][sg][i][j];
        rsv[gg][sg][i] = 1.0f / (sum + 1e-8f);
    }
    __syncthreads();
    for (int e = tid; e < NG * 200; e += 512) {
        int gg = e / 200, r = e - gg * 200;
        int sg = r / 100, rr = r - sg * 100;
        As[gg][sg][rr / 10][rr % 10] *= rsv[gg][sg][rr / 10];
    }
    __syncthreads();

    // per-thread packed output slot: u16 index (i stride 64)
    const int hslot = g * 640 + (k >> 1) * 4 + s * 2 + (k & 1);

    // ---- base layer fp16 dot2: Y=X@Wtop, Z=X@Wbot; H=tanh(An@Y + Z + b) ----
    {
        float accY[10], accZ[10];
        #pragma unroll
        for (int i = 0; i < 10; ++i) { accY[i] = 0.f; accZ[i] = 0.f; }
        const uint32_t* Wt = &WLu[(s * 32 + k) * 4];
        const uint32_t* Xg = &Xsu[g][0][0];
        for (int d2g = 0; d2g < 16; ++d2g) {
            uint4 wt = *reinterpret_cast<const uint4*>(Wt + d2g * 256);
            uint4 wb = *reinterpret_cast<const uint4*>(Wt + 4096 + d2g * 256);
            #pragma unroll
            for (int i = 0; i < 10; ++i) {
                uint4 xv = *reinterpret_cast<const uint4*>(Xg + i * 64 + d2g * 4);
                accY[i] = dot2(xv.x, wt.x, accY[i]);
                accY[i] = dot2(xv.y, wt.y, accY[i]);
                accY[i] = dot2(xv.z, wt.z, accY[i]);
                accY[i] = dot2(xv.w, wt.w, accY[i]);
                accZ[i] = dot2(xv.x, wb.x, accZ[i]);
                accZ[i] = dot2(xv.y, wb.y, accZ[i]);
                accZ[i] = dot2(xv.z, wb.z, accZ[i]);
                accZ[i] = dot2(xv.w, wb.w, accZ[i]);
            }
        }
        float bb = (s ? bnb : bpb)[k];
        uint16_t* Hw = reinterpret_cast<uint16_t*>(&H16a[0][0][0][0]);
        const float2* Ar = reinterpret_cast<const float2*>(&As[g][s][0][0]);
        #pragma unroll
        for (int i = 0; i < 10; ++i) {
            float acc = accZ[i] + bb;
            #pragma unroll
            for (int m = 0; m < 5; ++m) {
                float2 a2 = Ar[i * 5 + m];
                acc += a2.x * accY[2 * m] + a2.y * accY[2 * m + 1];
            }
            Hw[hslot + i * 64] = f2h(fast_tanh(acc));
        }
    }
    __syncthreads();

    // ---- two deep layers: packed fp16 + dot2, ping-pong H16a/H16b ----
    for (int l = 0; l < 2; ++l) {
        // restage deep weights packed fp16: [blk][cpg][s*32+k][j] (cp=cpg*4+j)
        // blk4 = w5 + (s==0 ? w7 : 0) (hp input), blk5 = w6 + (s==1 ? w7 : 0) (hn)
        for (int e = tid; e < 6144; e += 512) {
            int blk = e >> 10;
            int r = e & 1023;
            int cpg = r >> 8;
            int r2 = r & 255;
            int ln = r2 >> 2;
            int j = r2 & 3;
            int ss = ln >> 5, kk = ln & 31;
            int cp = cpg * 4 + j;
            const float* Ws = (ss ? Wnd : Wpd) + l * 7168;
            int rk = blk * 32 + 2 * cp;
            float f0 = Ws[rk * 32 + kk];
            float f1 = Ws[(rk + 1) * 32 + kk];
            if (blk >= 4 && ((blk == 4) == (ss == 0))) {
                f0 += Ws[(192 + 2 * cp) * 32 + kk];
                f1 += Ws[(193 + 2 * cp) * 32 + kk];
            }
            WLu[e] = pkh2(f0, f1);
        }
        __syncthreads();

        const uint32_t* Hin = l ? &H16b[0][0][0][0] : &H16a[0][0][0][0];
        uint16_t* Hout16 = reinterpret_cast<uint16_t*>(
            l ? &H16a[0][0][0][0] : &H16b[0][0][0][0]);

        float U12[10], U34[10], Dd[10];
        #pragma unroll
        for (int i = 0; i < 10; ++i) { U12[i] = 0.f; U34[i] = 0.f; Dd[i] = 0.f; }
        const uint32_t* Wd = &WLu[(s * 32 + k) * 4];   // + blk*1024 + cpg*256
        const uint32_t* Hg = Hin + g * 320;            // [j][cp][2], j stride 32

        for (int cpg = 0; cpg < 4; ++cpg) {
            uint4 w0 = *reinterpret_cast<const uint4*>(Wd + 0 * 1024 + cpg * 256);
            uint4 w1 = *reinterpret_cast<const uint4*>(Wd + 1 * 1024 + cpg * 256);
            uint4 w2 = *reinterpret_cast<const uint4*>(Wd + 2 * 1024 + cpg * 256);
            uint4 w3 = *reinterpret_cast<const uint4*>(Wd + 3 * 1024 + cpg * 256);
            uint4 w4 = *reinterpret_cast<const uint4*>(Wd + 4 * 1024 + cpg * 256);
            uint4 w5 = *reinterpret_cast<const uint4*>(Wd + 5 * 1024 + cpg * 256);
            #pragma unroll
            for (int j = 0; j < 10; ++j) {
                // ha = {hp(c0),hn(c0),hp(c1),hn(c1)}, hb = {hp(c2),hn(c2),hp(c3),hn(c3)}
                uint4 ha = *reinterpret_cast<const uint4*>(Hg + j * 32 + cpg * 8);
                uint4 hb = *reinterpret_cast<const uint4*>(Hg + j * 32 + cpg * 8 + 4);
                U12[j] = dot2(ha.x, w0.x, U12[j]);
                U12[j] = dot2(ha.z, w0.y, U12[j]);
                U12[j] = dot2(hb.x, w0.z, U12[j]);
                U12[j] = dot2(hb.z, w0.w, U12[j]);
                U12[j] = dot2(ha.y, w1.x, U12[j]);
                U12[j] = dot2(ha.w, w1.y, U12[j]);
                U12[j] = dot2(hb.y, w1.z, U12[j]);
                U12[j] = dot2(hb.w, w1.w, U12[j]);
                U34[j] = dot2(ha.x, w2.x, U34[j]);
                U34[j] = dot2(ha.z, w2.y, U34[j]);
                U34[j] = dot2(hb.x, w2.z, U34[j]);
                U34[j] = dot2(hb.z, w2.w, U34[j]);
                U34[j] = dot2(ha.y, w3.x, U34[j]);
                U34[j] = dot2(ha.w, w3.y, U34[j]);
                U34[j] = dot2(hb.y, w3.z, U34[j]);
                U34[j] = dot2(hb.w, w3.w, U34[j]);
                Dd[j]  = dot2(ha.x, w4.x, Dd[j]);
                Dd[j]  = dot2(ha.z, w4.y, Dd[j]);
                Dd[j]  = dot2(hb.x, w4.z, Dd[j]);
                Dd[j]  = dot2(hb.z, w4.w, Dd[j]);
                Dd[j]  = dot2(ha.y, w5.x, Dd[j]);
                Dd[j]  = dot2(ha.w, w5.y, Dd[j]);
                Dd[j]  = dot2(hb.y, w5.z, Dd[j]);
                Dd[j]  = dot2(hb.w, w5.w, Dd[j]);
            }
        }
        float bb = (s ? bnd : bpd)[l * 32 + k];
        const float2* Ap = reinterpret_cast<const float2*>(&As[g][0][0][0]);
        const float2* An = reinterpret_cast<const float2*>(&As[g][1][0][0]);
        #pragma unroll
        for (int i = 0; i < 10; ++i) {
            float acc = Dd[i] + bb;
            #pragma unroll
            for (int m = 0; m < 5; ++m) {
                float2 ap = Ap[i * 5 + m], an = An[i * 5 + m];
                acc += ap.x * U12[2 * m] + ap.y * U12[2 * m + 1]
                     + an.x * U34[2 * m] + an.y * U34[2 * m + 1];
            }
            Hout16[hslot + i * 64] = f2h(fast_tanh(acc));
        }
        __syncthreads();
    }

    // ---- z = cat([h_pos, h_neg], -1) as packed fp16 u32 (final H in H16a) ----
    {
        uint32_t* zb = z + (size_t)bt0 * 320;
        const uint32_t* Hf = &H16a[0][0][0][0];
        for (int e = tid; e < NG * 320; e += 512) {
            int gg = e / 320, r = e - gg * 320;
            int i = r >> 5, m = r & 31;
            zb[e] = Hf[gg * 320 + i * 32 + (m & 15) * 2 + (m >> 4)];
        }
    }
}

// ---------------------------------------------------------------------------
// LSTM v7 (MFMA, r4, measured ~209 us — best known): gates[256 x GL] =
// W[256x128] @ zh[128xGL] per step via mfma_f32_16x16x32_f16. W resident as
// A-frags in 64 VGPRs (step-invariant); zh read as 4 ds_read_b128/wave/step.
// Wave w computes gate section w (i,f,g,o). 2 barriers/step.
// ---------------------------------------------------------------------------
__global__ __launch_bounds__(256) void lstm_kernel(
    const uint32_t* __restrict__ zin,
    const float* __restrict__ W_ih,
    const float* __restrict__ W_hh,
    const float* __restrict__ b_ih,
    const float* __restrict__ b_hh,
    float* __restrict__ out)
{
    __shared__ __align__(16) uint32_t Zb[2][4][64][4]; // 8 KB [buf][kt][lane][i]
    __shared__ __align__(16) float gbuf[GL][264];      // 4.1 KB (stride 264: bank-spread)

    const int tid = threadIdx.x;
    const int w   = tid >> 6;        // wave = gate section (i,f,g,o)
    const int l   = tid & 63;        // lane
    const int lg  = l >> 4;          // lane group 0..3 (k-group / row-group)
    const int ln_ = l & 15;          // m (A) / n (B) index within tile
    const int p   = blockIdx.x % 10;
    const int b0  = (blockIdx.x / 10) * GL;

    // ---- A fragments: thread holds W[m][k-slice] for 4 row-tiles x 4 K-steps.
    // lane map: m = w*64 + tt*16 + ln_;  k = kt*32 + lg*8 + (2i, 2i+1)
    f16x8 wfrag[16];
    #pragma unroll
    for (int tt = 0; tt < 4; ++tt) {
        int m = w * 64 + tt * 16 + ln_;
        #pragma unroll
        for (int kt = 0; kt < 4; ++kt) {
            const float* Wsrc = (kt < 2) ? W_ih : W_hh;
            const float* base = Wsrc + ((size_t)p * 256 + m) * 64 + (kt & 1) * 32 + lg * 8;
            float4 v0 = *reinterpret_cast<const float4*>(base);
            float4 v1 = *reinterpret_cast<const float4*>(base + 4);
            f16x8 a;
            a[0] = (_Float16)v0.x; a[1] = (_Float16)v0.y;
            a[2] = (_Float16)v0.z; a[3] = (_Float16)v0.w;
            a[4] = (_Float16)v1.x; a[5] = (_Float16)v1.y;
            a[6] = (_Float16)v1.z; a[7] = (_Float16)v1.w;
            wfrag[tt * 4 + kt] = a;
        }
    }
    // bias folded into accumulator init: bias row m = w*64 + tt*16 + lg*4 + r
    f32x4v bias0, bias1, bias2, bias3;
    #pragma unroll
    for (int r = 0; r < 4; ++r) {
        int mb = w * 64 + lg * 4 + r;
        bias0[r] = b_ih[p * 256 + mb]      + b_hh[p * 256 + mb];
        bias1[r] = b_ih[p * 256 + mb + 16] + b_hh[p * 256 + mb + 16];
        bias2[r] = b_ih[p * 256 + mb + 32] + b_hh[p * 256 + mb + 32];
        bias3[r] = b_ih[p * 256 + mb + 48] + b_hh[p * 256 + mb + 48];
    }

    // ---- init: zero Zb (both buffers -> h(0)=0, unused cols stay 0) ----
    for (int e = tid; e < 2048; e += 256) (&Zb[0][0][0][0])[e] = 0u;
    // staging roles (tid>=128): game sgm, k-pair sj
    const int sgm = (tid >> 5) & 3, sj = tid & 31;
    uint32_t znext = 0;
    if (tid >= 128) {
        uint32_t z0 = zin[((size_t)(b0 + sgm) * 64 + 0) * 320 + p * 32 + sj];
        Zb[0][sj >> 4][((sj >> 2) & 3) * 16 + sgm][sj & 3] = z0;
        znext = zin[((size_t)(b0 + sgm) * 64 + 1) * 320 + p * 32 + sj];
    }
    __syncthreads();

    // activation roles (tid<128): game agm, h-pair ajh (h elems 2*ajh, 2*ajh+1)
    const int agm = tid >> 5, ajh = tid & 31;
    float c0r = 0.f, c1r = 0.f;

    for (int t = 0; t < 64; ++t) {
        const int buf = t & 1;
        // ---- gate phase: 4 B-frag reads + 16 MFMA ----
        uint4 q0 = *reinterpret_cast<const uint4*>(&Zb[buf][0][l][0]);
        uint4 q1 = *reinterpret_cast<const uint4*>(&Zb[buf][1][l][0]);
        uint4 q2 = *reinterpret_cast<const uint4*>(&Zb[buf][2][l][0]);
        uint4 q3 = *reinterpret_cast<const uint4*>(&Zb[buf][3][l][0]);
        f16x8 bf0 = __builtin_bit_cast(f16x8, q0);
        f16x8 bf1 = __builtin_bit_cast(f16x8, q1);
        f16x8 bf2 = __builtin_bit_cast(f16x8, q2);
        f16x8 bf3 = __builtin_bit_cast(f16x8, q3);
        f32x4v a0 = bias0, a1 = bias1, a2 = bias2, a3 = bias3;
        a0 = __builtin_amdgcn_mfma_f32_16x16x32_f16(wfrag[0],  bf0, a0, 0, 0, 0);
        a0 = __builtin_amdgcn_mfma_f32_16x16x32_f16(wfrag[1],  bf1, a0, 0, 0, 0);
        a0 = __builtin_amdgcn_mfma_f32_16x16x32_f16(wfrag[2],  bf2, a0, 0, 0, 0);
        a0 = __builtin_amdgcn_mfma_f32_16x16x32_f16(wfrag[3],  bf3, a0, 0, 0, 0);
        a1 = __builtin_amdgcn_mfma_f32_16x16x32_f16(wfrag[4],  bf0, a1, 0, 0, 0);
        a1 = __builtin_amdgcn_mfma_f32_16x16x32_f16(wfrag[5],  bf1, a1, 0, 0, 0);
        a1 = __builtin_amdgcn_mfma_f32_16x16x32_f16(wfrag[6],  bf2, a1, 0, 0, 0);
        a1 = __builtin_amdgcn_mfma_f32_16x16x32_f16(wfrag[7],  bf3, a1, 0, 0, 0);
        a2 = __builtin_amdgcn_mfma_f32_16x16x32_f16(wfrag[8],  bf0, a2, 0, 0, 0);
        a2 = __builtin_amdgcn_mfma_f32_16x16x32_f16(wfrag[9],  bf1, a2, 0, 0, 0);
        a2 = __builtin_amdgcn_mfma_f32_16x16x32_f16(wfrag[10], bf2, a2, 0, 0, 0);
        a2 = __builtin_amdgcn_mfma_f32_16x16x32_f16(wfrag[11], bf3, a2, 0, 0, 0);
        a3 = __builtin_amdgcn_mfma_f32_16x16x32_f16(wfrag[12], bf0, a3, 0, 0, 0);
        a3 = __builtin_amdgcn_mfma_f32_16x16x32_f16(wfrag[13], bf1, a3, 0, 0, 0);
        a3 = __builtin_amdgcn_mfma_f32_16x16x32_f16(wfrag[14], bf2, a3, 0, 0, 0);
        a3 = __builtin_amdgcn_mfma_f32_16x16x32_f16(wfrag[15], bf3, a3, 0, 0, 0);
        // D layout: row m = w*64 + tt*16 + lg*4 + reg, col n = ln_ (game)
        if (ln_ < GL) {
            *reinterpret_cast<f32x4v*>(&gbuf[ln_][w * 64 +  0 + lg * 4]) = a0;
            *reinterpret_cast<f32x4v*>(&gbuf[ln_][w * 64 + 16 + lg * 4]) = a1;
            *reinterpret_cast<f32x4v*>(&gbuf[ln_][w * 64 + 32 + lg * 4]) = a2;
            *reinterpret_cast<f32x4v*>(&gbuf[ln_][w * 64 + 48 + lg * 4]) = a3;
        }
        __syncthreads();

        // ---- act phase: tid<128 activation || tid>=128 z[t+1] staging ----
        if (tid < 128) {
            float2 gi = *reinterpret_cast<const float2*>(&gbuf[agm][  0 + 2 * ajh]);
            float2 gf = *reinterpret_cast<const float2*>(&gbuf[agm][ 64 + 2 * ajh]);
            float2 gg = *reinterpret_cast<const float2*>(&gbuf[agm][128 + 2 * ajh]);
            float2 go = *reinterpret_cast<const float2*>(&gbuf[agm][192 + 2 * ajh]);
            float c0 = sigmoidf_(gf.x) * c0r + sigmoidf_(gi.x) * fast_tanh(gg.x);
            float c1 = sigmoidf_(gf.y) * c1r + sigmoidf_(gi.y) * fast_tanh(gg.y);
            float h0 = sigmoidf_(go.x) * fast_tanh(c0);
            float h1 = sigmoidf_(go.y) * fast_tanh(c1);
            c0r = c0; c1r = c1;
            int jp = 32 + ajh;   // k-pair index of h pair
            Zb[buf ^ 1][jp >> 4][((jp >> 2) & 3) * 16 + agm][jp & 3] = pkh2(h0, h1);
            *reinterpret_cast<float2*>(
                &out[((size_t)(b0 + agm) * 64 + t) * 640 + p * 64 + 2 * ajh]) =
                make_float2(h0, h1);
        } else if (t < 63) {
            Zb[buf ^ 1][sj >> 4][((sj >> 2) & 3) * 16 + sgm][sj & 3] = znext;
            if (t < 62)
                znext = zin[((size_t)(b0 + sgm) * 64 + t + 2) * 320 + p * 32 + sj];
        }
        __syncthreads();
    }
}

extern "C" void kernel_launch(void* const* d_in, const int* in_sizes, int n_in,
                              void* d_out, int out_size, void* d_ws, size_t ws_size,
                              hipStream_t stream) {
    const float* x     = (const float*)d_in[0];
    const float* A_pos = (const float*)d_in[1];
    const float* A_neg = (const float*)d_in[2];
    const float* Wpb   = (const float*)d_in[3];
    const float* bpb   = (const float*)d_in[4];
    const float* Wnb   = (const float*)d_in[5];
    const float* bnb   = (const float*)d_in[6];
    const float* Wpd   = (const float*)d_in[7];
    const float* bpd   = (const float*)d_in[8];
    const float* Wnd   = (const float*)d_in[9];
    const float* bnd   = (const float*)d_in[10];
    const float* Wih   = (const float*)d_in[11];
    const float* Whh   = (const float*)d_in[12];
    const float* bih   = (const float*)d_in[13];
    const float* bhh   = (const float*)d_in[14];

    uint32_t* z = (uint32_t*)d_ws;     // [B,T,P,32] packed fp16 pairs = 20 MB
    float* out  = (float*)d_out;       // [B,T,P,64] fp32 = 40 MB

    sgcn_kernel<<<(Bg * Tg) / NG, 512, 0, stream>>>(
        x, A_pos, A_neg, Wpb, bpb, Wnb, bnb, Wpd, bpd, Wnd, bnd, z);
    lstm_kernel<<<(Bg / GL) * Pg, 256, 0, stream>>>(
        z, Wih, Whh, bih, bhh, out);
}

// Round 7
// 387.437 us; speedup vs baseline: 1.7781x; 1.2085x over previous
//
#include <hip/hip_runtime.h>
#include <stdint.h>

// Problem dims
#define Bg 256
#define Tg 64
#define Pg 10
#define NG 8   // graphs per sgcn block
#define GL 4   // lstm games per block

typedef _Float16 half2v __attribute__((ext_vector_type(2)));
typedef _Float16 f16x8 __attribute__((ext_vector_type(8)));
typedef float f32x4v __attribute__((ext_vector_type(4)));

__device__ __forceinline__ uint32_t pkh2(float lo, float hi) {
    half2v h; h.x = (_Float16)lo; h.y = (_Float16)hi;
    return __builtin_bit_cast(uint32_t, h);
}
__device__ __forceinline__ uint16_t f2h(float f) {
    _Float16 h = (_Float16)f;
    return __builtin_bit_cast(uint16_t, h);
}
__device__ __forceinline__ float h2f(uint16_t u) {
    _Float16 h = __builtin_bit_cast(_Float16, u);
    return (float)h;
}
__device__ __forceinline__ float sigmoidf_(float x) {
    return 1.0f / (1.0f + __expf(-x));
}
__device__ __forceinline__ float fast_tanh(float x) {
    float e = __expf(2.0f * x);
    return (e - 1.0f) / (e + 1.0f);
}
__device__ __forceinline__ f32x4v mfma16(uint4 a, uint4 b, f32x4v c) {
    return __builtin_amdgcn_mfma_f32_16x16x32_f16(
        __builtin_bit_cast(f16x8, a), __builtin_bit_cast(f16x8, b), c, 0, 0, 0);
}

// ---------------------------------------------------------------------------
// SGCN v8 (MFMA): per block NG=8 graphs -> M=80 rows = 5 Mtiles exactly.
//   base:  O1[80][128] = X[80][128] @ Wcat[128][128]  (cols Ypos|Zpos|Yneg|Zneg)
//   deep:  O2[80][192] = Hcat[80][64] @ Wcat[64][192] (cols U12|U34|D per sign,
//          w7 self-block pre-merged into D), x2 layers
// Epilogue (VALU, v5-style): per-graph A-mixing + tanh, H rescattered into
// fragment-ready LDS for the next layer's A-reads. Fragment maps are the
// lstm-r4-HW-validated ones: A/B k = kt*32+lg*8+e, lane = lg*16+(m|n);
// C/D row=(l>>4)*4+reg, col=l&15. All frag reads = lane-consecutive b128.
// LDS pool 80,960 B (overlaid phases) -> 2 blocks/CU.
// ---------------------------------------------------------------------------
__global__ __launch_bounds__(512) void sgcn_kernel(
    const float* __restrict__ x,
    const float* __restrict__ A_pos,
    const float* __restrict__ A_neg,
    const float* __restrict__ Wpb,
    const float* __restrict__ bpb,
    const float* __restrict__ Wnb,
    const float* __restrict__ bnb,
    const float* __restrict__ Wpd,
    const float* __restrict__ bpd,
    const float* __restrict__ Wnd,
    const float* __restrict__ bnd,
    uint32_t* __restrict__ z)
{
    // one overlaid pool, u32 offsets:
    //  As   @0      1600 u32  fp32 [8][2][10][10]
    //  rsv  @1600    160 u32
    //  XF   @1760   5120 u32  base A-frags [5][4][64][4]   (phase2+: HF/ZST)
    //  HF   @1760   2560 u32  deep A-frags [5][2][64][4]
    //  WFD  @4320   6144 u32  deep B-frags [12][2][64][4]
    //  WFB  @6880   8192 u32  base B-frags [8][4][64][4]
    //  O2   @10464  7680 u32  u16 [80][192]
    //  O1   @15072  5120 u32  u16 [80][128]
    __shared__ __align__(16) uint32_t S[20240];   // 80,960 B

    const int tid = threadIdx.x;
    const int bt0 = blockIdx.x * NG;
    const int wv = tid >> 6;          // wave id
    const int l  = tid & 63;          // lane
    const int lg = l >> 4, ln = l & 15;
    // epilogue roles (512 = 8g x 2s x 32k)
    const int g = tid >> 6, s = (tid >> 5) & 1, k = tid & 31;

    float* Asf  = reinterpret_cast<float*>(S);
    float* rsvf = reinterpret_cast<float*>(S + 1600);
    uint32_t* XF  = S + 1760;
    uint32_t* HF  = S + 1760;
    uint32_t* WFD = S + 4320;
    uint32_t* WFB = S + 6880;
    uint16_t* O2  = reinterpret_cast<uint16_t*>(S + 10464);
    uint16_t* O1  = reinterpret_cast<uint16_t*>(S + 15072);
    uint16_t* HFu = reinterpret_cast<uint16_t*>(S + 1760);
    uint16_t* ZST = reinterpret_cast<uint16_t*>(S + 1760);

    auto stageWFD = [&](int dl2) {
        for (int e = tid; e < 6144; e += 512) {
            int ep = e & 3, lane = (e >> 2) & 63, kt2 = (e >> 8) & 1, Nt = e >> 9;
            int n = lane & 15, lgg = lane >> 4;
            int kin = kt2 * 32 + lgg * 8 + ep * 2;      // pair (kin, kin+1)
            int c = Nt * 16 + n;                        // 0..191
            int s2 = c / 96, c2 = c - s2 * 96;
            const float* Ws = (s2 ? Wnd : Wpd) + dl2 * 7168;
            int bo = (c2 >> 5) * 2;                     // 0:U12 2:U34 4:D
            int col = c2 & 31;
            float f0 = Ws[(bo * 32 + kin) * 32 + col];
            float f1 = Ws[(bo * 32 + kin + 1) * 32 + col];
            if (bo == 4 && ((s2 == 0) == (kin < 32))) { // merge w7 self-block
                int kh = kin & 31;
                f0 += Ws[(192 + kh) * 32 + col];
                f1 += Ws[(192 + kh + 1) * 32 + col];
            }
            WFD[e] = pkh2(f0, f1);
        }
    };

    // ---- prologue staging: X frags, base W frags, raw adjacencies ----
    for (int e = tid; e < 5120; e += 512) {
        int grow = e >> 6, dp = e & 63, d = dp << 1;
        int gg = grow / 10, ii = grow - gg * 10;
        float2 v = *reinterpret_cast<const float2*>(
            x + (size_t)(bt0 + gg) * 1280 + ii * 128 + d);
        int Mt = grow >> 4, lnn = grow & 15;
        int kt = d >> 5, lgg = (d >> 3) & 3, ep = (d >> 1) & 3;
        XF[((Mt * 4 + kt) * 64 + lgg * 16 + lnn) * 4 + ep] = pkh2(v.x, v.y);
    }
    for (int e = tid; e < 8192; e += 512) {
        int ep = e & 3, lane = (e >> 2) & 63, kt = (e >> 8) & 3, Nt = e >> 10;
        int n = lane & 15, lgg = lane >> 4;
        int kk2 = kt * 32 + lgg * 8 + ep * 2;
        int c = Nt * 16 + n;                            // 0..127
        const float* Wsrc = (c & 64) ? Wnb : Wpb;
        int cc = c & 63;
        int rb = (cc & 32) ? 128 : 0;                   // Z block = rows 128..255
        int col = cc & 31;
        WFB[e] = pkh2(Wsrc[(rb + kk2) * 32 + col], Wsrc[(rb + kk2 + 1) * 32 + col]);
    }
    for (int e = tid; e < 1600; e += 512) {
        int gg = e / 200, r = e - gg * 200;
        int sg = r / 100, rr = r - sg * 100;
        Asf[(gg * 2 + sg) * 100 + rr] =
            (sg ? A_neg : A_pos)[(size_t)(bt0 + gg) * 100 + rr];
    }
    __syncthreads();
    if (tid < 160) {
        int gg = tid / 20, r = tid % 20, sg = r / 10, i = r % 10;
        float sum = 0.f;
        #pragma unroll
        for (int j = 0; j < 10; ++j) sum += Asf[(gg * 2 + sg) * 100 + i * 10 + j];
        rsvf[(gg * 2 + sg) * 10 + i] = 1.0f / (sum + 1e-8f);
    }
    __syncthreads();
    for (int e = tid; e < 1600; e += 512) {
        int gg = e / 200, r = e - gg * 200;
        int sg = r / 100, rr = r - sg * 100;
        Asf[(gg * 2 + sg) * 100 + rr] *= rsvf[(gg * 2 + sg) * 10 + rr / 10];
    }
    __syncthreads();

    // ---- base MFMA: wave wv owns Ntile wv ----
    {
        uint4 b0 = *reinterpret_cast<const uint4*>(WFB + ((wv * 4 + 0) * 64 + l) * 4);
        uint4 b1 = *reinterpret_cast<const uint4*>(WFB + ((wv * 4 + 1) * 64 + l) * 4);
        uint4 b2 = *reinterpret_cast<const uint4*>(WFB + ((wv * 4 + 2) * 64 + l) * 4);
        uint4 b3 = *reinterpret_cast<const uint4*>(WFB + ((wv * 4 + 3) * 64 + l) * 4);
        #pragma unroll
        for (int Mt = 0; Mt < 5; ++Mt) {
            uint4 a0 = *reinterpret_cast<const uint4*>(XF + ((Mt * 4 + 0) * 64 + l) * 4);
            uint4 a1 = *reinterpret_cast<const uint4*>(XF + ((Mt * 4 + 1) * 64 + l) * 4);
            uint4 a2 = *reinterpret_cast<const uint4*>(XF + ((Mt * 4 + 2) * 64 + l) * 4);
            uint4 a3 = *reinterpret_cast<const uint4*>(XF + ((Mt * 4 + 3) * 64 + l) * 4);
            f32x4v c = {0.f, 0.f, 0.f, 0.f};
            c = mfma16(a0, b0, c);
            c = mfma16(a1, b1, c);
            c = mfma16(a2, b2, c);
            c = mfma16(a3, b3, c);
            #pragma unroll
            for (int r = 0; r < 4; ++r)
                O1[(Mt * 16 + lg * 4 + r) * 128 + wv * 16 + ln] = f2h(c[r]);
        }
    }
    __syncthreads();

    // ---- epi1: H = tanh(A_s @ Y + Z + b) -> HF;  stage deep W layer 0 ----
    stageWFD(0);
    {
        const float2* Ar = reinterpret_cast<const float2*>(Asf + (g * 2 + s) * 100);
        float Yv[10];
        #pragma unroll
        for (int j = 0; j < 10; ++j)
            Yv[j] = h2f(O1[(g * 10 + j) * 128 + s * 64 + k]);
        float bb = (s ? bnb : bpb)[k];
        #pragma unroll
        for (int i = 0; i < 10; ++i) {
            float acc = h2f(O1[(g * 10 + i) * 128 + s * 64 + 32 + k]) + bb;
            #pragma unroll
            for (int m = 0; m < 5; ++m) {
                float2 a2 = Ar[i * 5 + m];
                acc += a2.x * Yv[2 * m] + a2.y * Yv[2 * m + 1];
            }
            int row = g * 10 + i;
            HFu[(((row >> 4) * 2 + s) * 64 + ((k >> 3) & 3) * 16 + (row & 15)) * 8 + (k & 7)]
                = f2h(fast_tanh(acc));
        }
    }
    __syncthreads();

    // ---- two deep layers ----
    for (int dl = 0; dl < 2; ++dl) {
        // deep MFMA: 12 Ntiles over 8 waves (waves 0-3 take a second tile)
        {
            #pragma unroll
            for (int pass = 0; pass < 2; ++pass) {
                int Nt = wv + pass * 8;
                if (pass == 1 && wv >= 4) break;
                uint4 b0 = *reinterpret_cast<const uint4*>(WFD + ((Nt * 2 + 0) * 64 + l) * 4);
                uint4 b1 = *reinterpret_cast<const uint4*>(WFD + ((Nt * 2 + 1) * 64 + l) * 4);
                #pragma unroll
                for (int Mt = 0; Mt < 5; ++Mt) {
                    uint4 a0 = *reinterpret_cast<const uint4*>(HF + ((Mt * 2 + 0) * 64 + l) * 4);
                    uint4 a1 = *reinterpret_cast<const uint4*>(HF + ((Mt * 2 + 1) * 64 + l) * 4);
                    f32x4v c = {0.f, 0.f, 0.f, 0.f};
                    c = mfma16(a0, b0, c);
                    c = mfma16(a1, b1, c);
                    #pragma unroll
                    for (int r = 0; r < 4; ++r)
                        O2[(Mt * 16 + lg * 4 + r) * 192 + Nt * 16 + ln] = f2h(c[r]);
                }
            }
        }
        __syncthreads();

        // epilogue: H' = tanh(Apos@U12 + Aneg@U34 + D + b)
        if (dl == 0) stageWFD(1);    // restage deep weights for layer 1
        {
            const float2* Ap = reinterpret_cast<const float2*>(Asf + g * 200);
            const float2* An = reinterpret_cast<const float2*>(Asf + g * 200 + 100);
            float U1[10], U3[10];
            #pragma unroll
            for (int j = 0; j < 10; ++j) {
                U1[j] = h2f(O2[(g * 10 + j) * 192 + s * 96 + k]);
                U3[j] = h2f(O2[(g * 10 + j) * 192 + s * 96 + 32 + k]);
            }
            float bb = (s ? bnd : bpd)[dl * 32 + k];
            #pragma unroll
            for (int i = 0; i < 10; ++i) {
                float acc = h2f(O2[(g * 10 + i) * 192 + s * 96 + 64 + k]) + bb;
                #pragma unroll
                for (int m = 0; m < 5; ++m) {
                    float2 ap = Ap[i * 5 + m], an = An[i * 5 + m];
                    acc += ap.x * U1[2 * m] + ap.y * U1[2 * m + 1]
                         + an.x * U3[2 * m] + an.y * U3[2 * m + 1];
                }
                float hv = fast_tanh(acc);
                int row = g * 10 + i;
                if (dl == 0)
                    HFu[(((row >> 4) * 2 + s) * 64 + ((k >> 3) & 3) * 16 + (row & 15)) * 8 + (k & 7)]
                        = f2h(hv);
                else
                    ZST[row * 64 + s * 32 + k] = f2h(hv);
            }
        }
        __syncthreads();
    }

    // ---- z output: ZST u16 [80][64] -> packed u32, coalesced ----
    {
        const uint32_t* Zu = reinterpret_cast<const uint32_t*>(ZST);
        for (int e = tid; e < 2560; e += 512)
            z[(size_t)bt0 * 320 + e] = Zu[e];
    }
}

// ---------------------------------------------------------------------------
// LSTM v7 (MFMA, r4/r6, measured ~217 us — kept byte-identical this round):
// gates[256 x GL] = W[256x128] @ zh[128xGL] per step via mfma_f32_16x16x32_f16.
// ---------------------------------------------------------------------------
__global__ __launch_bounds__(256) void lstm_kernel(
    const uint32_t* __restrict__ zin,
    const float* __restrict__ W_ih,
    const float* __restrict__ W_hh,
    const float* __restrict__ b_ih,
    const float* __restrict__ b_hh,
    float* __restrict__ out)
{
    __shared__ __align__(16) uint32_t Zb[2][4][64][4]; // 8 KB [buf][kt][lane][i]
    __shared__ __align__(16) float gbuf[GL][264];      // 4.1 KB (stride 264: bank-spread)

    const int tid = threadIdx.x;
    const int w   = tid >> 6;        // wave = gate section (i,f,g,o)
    const int l   = tid & 63;        // lane
    const int lg  = l >> 4;          // lane group 0..3 (k-group / row-group)
    const int ln_ = l & 15;          // m (A) / n (B) index within tile
    const int p   = blockIdx.x % 10;
    const int b0  = (blockIdx.x / 10) * GL;

    // ---- A fragments: thread holds W[m][k-slice] for 4 row-tiles x 4 K-steps.
    // lane map: m = w*64 + tt*16 + ln_;  k = kt*32 + lg*8 + (2i, 2i+1)
    f16x8 wfrag[16];
    #pragma unroll
    for (int tt = 0; tt < 4; ++tt) {
        int m = w * 64 + tt * 16 + ln_;
        #pragma unroll
        for (int kt = 0; kt < 4; ++kt) {
            const float* Wsrc = (kt < 2) ? W_ih : W_hh;
            const float* base = Wsrc + ((size_t)p * 256 + m) * 64 + (kt & 1) * 32 + lg * 8;
            float4 v0 = *reinterpret_cast<const float4*>(base);
            float4 v1 = *reinterpret_cast<const float4*>(base + 4);
            f16x8 a;
            a[0] = (_Float16)v0.x; a[1] = (_Float16)v0.y;
            a[2] = (_Float16)v0.z; a[3] = (_Float16)v0.w;
            a[4] = (_Float16)v1.x; a[5] = (_Float16)v1.y;
            a[6] = (_Float16)v1.z; a[7] = (_Float16)v1.w;
            wfrag[tt * 4 + kt] = a;
        }
    }
    // bias folded into accumulator init: bias row m = w*64 + tt*16 + lg*4 + r
    f32x4v bias0, bias1, bias2, bias3;
    #pragma unroll
    for (int r = 0; r < 4; ++r) {
        int mb = w * 64 + lg * 4 + r;
        bias0[r] = b_ih[p * 256 + mb]      + b_hh[p * 256 + mb];
        bias1[r] = b_ih[p * 256 + mb + 16] + b_hh[p * 256 + mb + 16];
        bias2[r] = b_ih[p * 256 + mb + 32] + b_hh[p * 256 + mb + 32];
        bias3[r] = b_ih[p * 256 + mb + 48] + b_hh[p * 256 + mb + 48];
    }

    // ---- init: zero Zb (both buffers -> h(0)=0, unused cols stay 0) ----
    for (int e = tid; e < 2048; e += 256) (&Zb[0][0][0][0])[e] = 0u;
    // staging roles (tid>=128): game sgm, k-pair sj
    const int sgm = (tid >> 5) & 3, sj = tid & 31;
    uint32_t znext = 0;
    if (tid >= 128) {
        uint32_t z0 = zin[((size_t)(b0 + sgm) * 64 + 0) * 320 + p * 32 + sj];
        Zb[0][sj >> 4][((sj >> 2) & 3) * 16 + sgm][sj & 3] = z0;
        znext = zin[((size_t)(b0 + sgm) * 64 + 1) * 320 + p * 32 + sj];
    }
    __syncthreads();

    // activation roles (tid<128): game agm, h-pair ajh (h elems 2*ajh, 2*ajh+1)
    const int agm = tid >> 5, ajh = tid & 31;
    float c0r = 0.f, c1r = 0.f;

    for (int t = 0; t < 64; ++t) {
        const int buf = t & 1;
        // ---- gate phase: 4 B-frag reads + 16 MFMA ----
        uint4 q0 = *reinterpret_cast<const uint4*>(&Zb[buf][0][l][0]);
        uint4 q1 = *reinterpret_cast<const uint4*>(&Zb[buf][1][l][0]);
        uint4 q2 = *reinterpret_cast<const uint4*>(&Zb[buf][2][l][0]);
        uint4 q3 = *reinterpret_cast<const uint4*>(&Zb[buf][3][l][0]);
        f16x8 bf0 = __builtin_bit_cast(f16x8, q0);
        f16x8 bf1 = __builtin_bit_cast(f16x8, q1);
        f16x8 bf2 = __builtin_bit_cast(f16x8, q2);
        f16x8 bf3 = __builtin_bit_cast(f16x8, q3);
        f32x4v a0 = bias0, a1 = bias1, a2 = bias2, a3 = bias3;
        a0 = __builtin_amdgcn_mfma_f32_16x16x32_f16(wfrag[0],  bf0, a0, 0, 0, 0);
        a0 = __builtin_amdgcn_mfma_f32_16x16x32_f16(wfrag[1],  bf1, a0, 0, 0, 0);
        a0 = __builtin_amdgcn_mfma_f32_16x16x32_f16(wfrag[2],  bf2, a0, 0, 0, 0);
        a0 = __builtin_amdgcn_mfma_f32_16x16x32_f16(wfrag[3],  bf3, a0, 0, 0, 0);
        a1 = __builtin_amdgcn_mfma_f32_16x16x32_f16(wfrag[4],  bf0, a1, 0, 0, 0);
        a1 = __builtin_amdgcn_mfma_f32_16x16x32_f16(wfrag[5],  bf1, a1, 0, 0, 0);
        a1 = __builtin_amdgcn_mfma_f32_16x16x32_f16(wfrag[6],  bf2, a1, 0, 0, 0);
        a1 = __builtin_amdgcn_mfma_f32_16x16x32_f16(wfrag[7],  bf3, a1, 0, 0, 0);
        a2 = __builtin_amdgcn_mfma_f32_16x16x32_f16(wfrag[8],  bf0, a2, 0, 0, 0);
        a2 = __builtin_amdgcn_mfma_f32_16x16x32_f16(wfrag[9],  bf1, a2, 0, 0, 0);
        a2 = __builtin_amdgcn_mfma_f32_16x16x32_f16(wfrag[10], bf2, a2, 0, 0, 0);
        a2 = __builtin_amdgcn_mfma_f32_16x16x32_f16(wfrag[11], bf3, a2, 0, 0, 0);
        a3 = __builtin_amdgcn_mfma_f32_16x16x32_f16(wfrag[12], bf0, a3, 0, 0, 0);
        a3 = __builtin_amdgcn_mfma_f32_16x16x32_f16(wfrag[13], bf1, a3, 0, 0, 0);
        a3 = __builtin_amdgcn_mfma_f32_16x16x32_f16(wfrag[14], bf2, a3, 0, 0, 0);
        a3 = __builtin_amdgcn_mfma_f32_16x16x32_f16(wfrag[15], bf3, a3, 0, 0, 0);
        // D layout: row m = w*64 + tt*16 + lg*4 + reg, col n = ln_ (game)
        if (ln_ < GL) {
            *reinterpret_cast<f32x4v*>(&gbuf[ln_][w * 64 +  0 + lg * 4]) = a0;
            *reinterpret_cast<f32x4v*>(&gbuf[ln_][w * 64 + 16 + lg * 4]) = a1;
            *reinterpret_cast<f32x4v*>(&gbuf[ln_][w * 64 + 32 + lg * 4]) = a2;
            *reinterpret_cast<f32x4v*>(&gbuf[ln_][w * 64 + 48 + lg * 4]) = a3;
        }
        __syncthreads();

        // ---- act phase: tid<128 activation || tid>=128 z[t+1] staging ----
        if (tid < 128) {
            float2 gi = *reinterpret_cast<const float2*>(&gbuf[agm][  0 + 2 * ajh]);
            float2 gf = *reinterpret_cast<const float2*>(&gbuf[agm][ 64 + 2 * ajh]);
            float2 gg = *reinterpret_cast<const float2*>(&gbuf[agm][128 + 2 * ajh]);
            float2 go = *reinterpret_cast<const float2*>(&gbuf[agm][192 + 2 * ajh]);
            float c0 = sigmoidf_(gf.x) * c0r + sigmoidf_(gi.x) * fast_tanh(gg.x);
            float c1 = sigmoidf_(gf.y) * c1r + sigmoidf_(gi.y) * fast_tanh(gg.y);
            float h0 = sigmoidf_(go.x) * fast_tanh(c0);
            float h1 = sigmoidf_(go.y) * fast_tanh(c1);
            c0r = c0; c1r = c1;
            int jp = 32 + ajh;   // k-pair index of h pair
            Zb[buf ^ 1][jp >> 4][((jp >> 2) & 3) * 16 + agm][jp & 3] = pkh2(h0, h1);
            *reinterpret_cast<float2*>(
                &out[((size_t)(b0 + agm) * 64 + t) * 640 + p * 64 + 2 * ajh]) =
                make_float2(h0, h1);
        } else if (t < 63) {
            Zb[buf ^ 1][sj >> 4][((sj >> 2) & 3) * 16 + sgm][sj & 3] = znext;
            if (t < 62)
                znext = zin[((size_t)(b0 + sgm) * 64 + t + 2) * 320 + p * 32 + sj];
        }
        __syncthreads();
    }
}

extern "C" void kernel_launch(void* const* d_in, const int* in_sizes, int n_in,
                              void* d_out, int out_size, void* d_ws, size_t ws_size,
                              hipStream_t stream) {
    const float* x     = (const float*)d_in[0];
    const float* A_pos = (const float*)d_in[1];
    const float* A_neg = (const float*)d_in[2];
    const float* Wpb   = (const float*)d_in[3];
    const float* bpb   = (const float*)d_in[4];
    const float* Wnb   = (const float*)d_in[5];
    const float* bnb   = (const float*)d_in[6];
    const float* Wpd   = (const float*)d_in[7];
    const float* bpd   = (const float*)d_in[8];
    const float* Wnd   = (const float*)d_in[9];
    const float* bnd   = (const float*)d_in[10];
    const float* Wih   = (const float*)d_in[11];
    const float* Whh   = (const float*)d_in[12];
    const float* bih   = (const float*)d_in[13];
    const float* bhh   = (const float*)d_in[14];

    uint32_t* z = (uint32_t*)d_ws;     // [B,T,P,32] packed fp16 pairs = 20 MB
    float* out  = (float*)d_out;       // [B,T,P,64] fp32 = 40 MB

    sgcn_kernel<<<(Bg * Tg) / NG, 512, 0, stream>>>(
        x, A_pos, A_neg, Wpb, bpb, Wnb, bnb, Wpd, bpd, Wnd, bnd, z);
    lstm_kernel<<<(Bg / GL) * Pg, 256, 0, stream>>>(
        z, Wih, Whh, bih, bhh, out);
}